// Round 1
// baseline (2171.634 us; speedup 1.0000x reference)
//
#include <hip/hip_runtime.h>

// GaussianMRIModel: splat 25000 anisotropic 3D Gaussians into a 160^3 x 2 fp32 volume.
// Strategy: one block per Gaussian (scatter). Factorized quadratic form:
//   e = p00*dz^2 + dz*(2p01*dy + 2p02*dx) + (p11*dy^2 + 2p12*dy*dx + p22*dx^2)
// Precompute z-terms (<=20) and (y,x)-plane terms (<=400) in LDS; inner loop is
// fma + add + v_exp_f32 + 2 global_atomic_add_f32 per cell.

namespace {
constexpr int GD = 160, GH = 160, GW = 160;
constexpr int NPTS = 25000;
constexpr int PATCH = 20;
}

__global__ __launch_bounds__(256) void gauss_splat(
    const float* __restrict__ centers,
    const float* __restrict__ log_scales,
    const float* __restrict__ quats,
    const float* __restrict__ rho,
    float* __restrict__ out)
{
    const int n = blockIdx.x;
    const int tid = threadIdx.x;

    // ---- per-point parameters (block-uniform, computed redundantly per thread) ----
    const float r0 = rho[n * 2 + 0];
    const float r1 = rho[n * 2 + 1];
    const float s0 = __expf(log_scales[n * 3 + 0]);
    const float s1 = __expf(log_scales[n * 3 + 1]);
    const float s2 = __expf(log_scales[n * 3 + 2]);

    const float smax = fmaxf(s0, fmaxf(s1, s2));
    const float rad = smax * 3.0f;            // RADIUS_FACTOR
    const float amp2 = r0 * r0 + r1 * r1;
    // valid = (amp >= 1e-6) & (rad >= 1e-3); block-uniform early exit is safe.
    if (!(amp2 >= 1e-12f) || !(rad >= 1e-3f)) return;

    const float cvz = centers[n * 3 + 0] * (float)(GD - 1);
    const float cvy = centers[n * 3 + 1] * (float)(GH - 1);
    const float cvx = centers[n * 3 + 2] * (float)(GW - 1);

    const int bz = (int)floorf(cvz - rad);
    const int by = (int)floorf(cvy - rad);
    const int bx = (int)floorf(cvx - rad);
    const int hz = (int)ceilf(cvz + rad);
    const int hy = (int)ceilf(cvy + rad);
    const int hx = (int)ceilf(cvx + rad);

    // mask in reference: idx >= 0 && idx < dim && idx <= hi, idx in [base, base+19]
    const int loz = max(bz, 0), upz = min(min(hz, GD - 1), bz + PATCH - 1);
    const int loy = max(by, 0), upy = min(min(hy, GH - 1), by + PATCH - 1);
    const int lox = max(bx, 0), upx = min(min(hx, GW - 1), bx + PATCH - 1);
    const int cntz = upz - loz + 1;
    const int cnty = upy - loy + 1;
    const int cntx = upx - lox + 1;
    if (cntz <= 0 || cnty <= 0 || cntx <= 0) return;

    // quaternion -> rotation (normalize with clip(norm, 1e-6))
    const float q0 = quats[n * 4 + 0], q1 = quats[n * 4 + 1];
    const float q2 = quats[n * 4 + 2], q3 = quats[n * 4 + 3];
    float qn = sqrtf(q0 * q0 + q1 * q1 + q2 * q2 + q3 * q3);
    qn = fmaxf(qn, 1e-6f);
    const float w = q0 / qn, x = q1 / qn, y = q2 / qn, z = q3 / qn;

    const float R00 = w * w + x * x - y * y - z * z;
    const float R01 = 2.f * (x * y - w * z);
    const float R02 = 2.f * (x * z + w * y);
    const float R10 = 2.f * (x * y + w * z);
    const float R11 = w * w - x * x + y * y - z * z;
    const float R12 = 2.f * (y * z - w * x);
    const float R20 = 2.f * (x * z - w * y);
    const float R21 = 2.f * (y * z + w * x);
    const float R22 = w * w - x * x - y * y + z * z;

    const float c0 = fmaxf(s0, 1e-4f); const float i0 = 1.f / (c0 * c0);
    const float c1 = fmaxf(s1, 1e-4f); const float i1 = 1.f / (c1 * c1);
    const float c2 = fmaxf(s2, 1e-4f); const float i2 = 1.f / (c2 * c2);

    // prec = R diag(inv) R^T
    const float p00 = R00 * R00 * i0 + R01 * R01 * i1 + R02 * R02 * i2;
    const float p01 = R00 * R10 * i0 + R01 * R11 * i1 + R02 * R12 * i2;
    const float p02 = R00 * R20 * i0 + R01 * R21 * i1 + R02 * R22 * i2;
    const float p11 = R10 * R10 * i0 + R11 * R11 * i1 + R12 * R12 * i2;
    const float p12 = R10 * R20 * i0 + R11 * R21 * i1 + R12 * R22 * i2;
    const float p22 = R20 * R20 * i0 + R21 * R21 * i1 + R22 * R22 * i2;

    // ---- LDS precompute: z-terms and (y,x)-plane terms ----
    __shared__ float sAz[PATCH];          // p00*dz^2
    __shared__ float sDz[PATCH];          // dz
    __shared__ float sA[PATCH * PATCH];   // p11*dy^2 + 2p12*dy*dx + p22*dx^2
    __shared__ float sB[PATCH * PATCH];   // 2*(p01*dy + p02*dx)

    if (tid < cntz) {
        const float dz = (float)(loz + tid) - cvz;
        sAz[tid] = p00 * dz * dz;
        sDz[tid] = dz;
    }
    const int pairs = cnty * cntx;
    for (int p = tid; p < pairs; p += 256) {
        const int cy = p / cntx;
        const int cxp = p - cy * cntx;
        const float dy = (float)(loy + cy) - cvy;
        const float dx = (float)(lox + cxp) - cvx;
        sA[p] = p11 * dy * dy + 2.f * p12 * dy * dx + p22 * dx * dx;
        sB[p] = 2.f * (p01 * dy + p02 * dx);
    }
    __syncthreads();

    // ---- main scatter loop: each thread owns (y,x) pairs, walks z serially ----
    for (int p = tid; p < pairs; p += 256) {
        const int cy = p / cntx;
        const int cxp = p - cy * cntx;
        const int iy = loy + cy;
        const int ix = lox + cxp;
        const float A = sA[p];
        const float B = sB[p];
        float* rowbase = out + ((size_t)iy * GW + ix) * 2;
        for (int cz = 0; cz < cntz; ++cz) {
            const float t = -0.5f * (sAz[cz] + fmaf(sDz[cz], B, A));
            // skip numerically-invisible contributions (w < ~1e-6; threshold is 1.09e-2)
            if (t > -13.9f) {
                const float wgt = __expf(t);
                float* dst = rowbase + (size_t)(loz + cz) * (GH * GW * 2);
                unsafeAtomicAdd(dst, wgt * r0);
                unsafeAtomicAdd(dst + 1, wgt * r1);
            }
        }
    }
}

extern "C" void kernel_launch(void* const* d_in, const int* in_sizes, int n_in,
                              void* d_out, int out_size, void* d_ws, size_t ws_size,
                              hipStream_t stream) {
    const float* centers    = (const float*)d_in[0];
    const float* log_scales = (const float*)d_in[1];
    const float* quats      = (const float*)d_in[2];
    const float* rho        = (const float*)d_in[3];
    float* out = (float*)d_out;

    // d_out is poisoned to 0xAA before every timed call — zero it ourselves.
    hipMemsetAsync(d_out, 0, (size_t)out_size * sizeof(float), stream);
    gauss_splat<<<NPTS, 256, 0, stream>>>(centers, log_scales, quats, rho, out);
}

// Round 2
// 268.329 us; speedup vs baseline: 8.0932x; 8.0932x over previous
//
#include <hip/hip_runtime.h>

// GaussianMRIModel: splat 25000 anisotropic 3D Gaussians into 160^3 x 2 fp32.
// R1: atomic scatter (2.2 GB atomic write-through, 1.05 TB/s bound) -> binned
// GATHER. prep_bin computes per-Gaussian quadratic struct + tile buckets;
// gather evaluates per 8^3 tile, accumulates in registers, writes once.

namespace {
constexpr int GD = 160, GH = 160, GW = 160;
constexpr int NPTS = 25000;
constexpr int PATCH = 20;
constexpr int TS  = 8;              // tile edge
constexpr int TPD = GD / TS;        // 20 tiles per dim
constexpr int NT  = TPD * TPD * TPD;// 8000 tiles
constexpr int CAP = 384;            // per-tile bucket capacity (mean ~94)
constexpr int PSTRIDE = 16;         // floats per gaussian param struct
}

// Param struct layout (16 floats, 4x float4):
//  [0] q00  [1] q01  [2] q02  [3] q11      (q = -0.5*p for diag, -p for cross)
//  [4] q12  [5] q22  [6] cvz  [7] cvy
//  [8] cvx  [9] r0  [10] r1  [11] loPack (loz|loy<<8|lox<<16|upz<<24)
// [12] upPack (upy|upx<<8)  [13..15] unused

__global__ void prep_bin(const float* __restrict__ centers,
                         const float* __restrict__ log_scales,
                         const float* __restrict__ quats,
                         const float* __restrict__ rho,
                         float* __restrict__ params,
                         int* __restrict__ counts,
                         unsigned short* __restrict__ list)
{
    const int gid = blockIdx.x * blockDim.x + threadIdx.x;
    if (gid >= NPTS) return;

    const float r0 = rho[gid * 2 + 0];
    const float r1 = rho[gid * 2 + 1];
    const float s0 = __expf(log_scales[gid * 3 + 0]);
    const float s1 = __expf(log_scales[gid * 3 + 1]);
    const float s2 = __expf(log_scales[gid * 3 + 2]);

    const float smax = fmaxf(s0, fmaxf(s1, s2));
    const float rad  = smax * 3.0f;           // RADIUS_FACTOR
    const float amp2 = r0 * r0 + r1 * r1;

    const float cvz = centers[gid * 3 + 0] * (float)(GD - 1);
    const float cvy = centers[gid * 3 + 1] * (float)(GH - 1);
    const float cvx = centers[gid * 3 + 2] * (float)(GW - 1);

    const int bz = (int)floorf(cvz - rad);
    const int by = (int)floorf(cvy - rad);
    const int bx = (int)floorf(cvx - rad);
    const int hz = (int)ceilf(cvz + rad);
    const int hy = (int)ceilf(cvy + rad);
    const int hx = (int)ceilf(cvx + rad);

    // reference mask: idx>=0 && idx<dim && idx<=hi, idx in [base, base+19]
    const int loz = max(bz, 0), upz = min(min(hz, GD - 1), bz + PATCH - 1);
    const int loy = max(by, 0), upy = min(min(hy, GH - 1), by + PATCH - 1);
    const int lox = max(bx, 0), upx = min(min(hx, GW - 1), bx + PATCH - 1);

    const bool valid = (amp2 >= 1e-12f) && (rad >= 1e-3f) &&
                       (upz >= loz) && (upy >= loy) && (upx >= lox);

    // quaternion -> rotation
    const float q0 = quats[gid * 4 + 0], q1 = quats[gid * 4 + 1];
    const float q2 = quats[gid * 4 + 2], q3 = quats[gid * 4 + 3];
    float qn = sqrtf(q0 * q0 + q1 * q1 + q2 * q2 + q3 * q3);
    qn = fmaxf(qn, 1e-6f);
    const float w = q0 / qn, x = q1 / qn, y = q2 / qn, z = q3 / qn;

    const float R00 = w * w + x * x - y * y - z * z;
    const float R01 = 2.f * (x * y - w * z);
    const float R02 = 2.f * (x * z + w * y);
    const float R10 = 2.f * (x * y + w * z);
    const float R11 = w * w - x * x + y * y - z * z;
    const float R12 = 2.f * (y * z - w * x);
    const float R20 = 2.f * (x * z - w * y);
    const float R21 = 2.f * (y * z + w * x);
    const float R22 = w * w - x * x - y * y + z * z;

    const float c0 = fmaxf(s0, 1e-4f); const float i0 = 1.f / (c0 * c0);
    const float c1 = fmaxf(s1, 1e-4f); const float i1 = 1.f / (c1 * c1);
    const float c2 = fmaxf(s2, 1e-4f); const float i2 = 1.f / (c2 * c2);

    const float p00 = R00 * R00 * i0 + R01 * R01 * i1 + R02 * R02 * i2;
    const float p01 = R00 * R10 * i0 + R01 * R11 * i1 + R02 * R12 * i2;
    const float p02 = R00 * R20 * i0 + R01 * R21 * i1 + R02 * R22 * i2;
    const float p11 = R10 * R10 * i0 + R11 * R11 * i1 + R12 * R12 * i2;
    const float p12 = R10 * R20 * i0 + R11 * R21 * i1 + R12 * R22 * i2;
    const float p22 = R20 * R20 * i0 + R21 * R21 * i1 + R22 * R22 * i2;

    // fold -0.5 so gather computes t = -0.5*e directly
    const int zl = valid ? loz : 0, zu = valid ? upz : 0;
    const int yl = valid ? loy : 0, yu = valid ? upy : 0;
    const int xl = valid ? lox : 0, xu = valid ? upx : 0;
    const int loPack = zl | (yl << 8) | (xl << 16) | (zu << 24);
    const int upPack = yu | (xu << 8);

    float4* P = reinterpret_cast<float4*>(params + (size_t)gid * PSTRIDE);
    P[0] = make_float4(-0.5f * p00, -p01, -p02, -0.5f * p11);
    P[1] = make_float4(-p12, -0.5f * p22, cvz, cvy);
    P[2] = make_float4(cvx, r0, r1, __int_as_float(loPack));
    P[3] = make_float4(__int_as_float(upPack), 0.f, 0.f, 0.f);

    if (!valid) return;

    const int tz0 = loz >> 3, tz1 = upz >> 3;
    const int ty0 = loy >> 3, ty1 = upy >> 3;
    const int tx0 = lox >> 3, tx1 = upx >> 3;
    for (int tz = tz0; tz <= tz1; ++tz)
        for (int ty = ty0; ty <= ty1; ++ty)
            for (int tx = tx0; tx <= tx1; ++tx) {
                const int t = (tz * TPD + ty) * TPD + tx;
                const int pos = atomicAdd(&counts[t], 1);
                if (pos < CAP) list[(size_t)t * CAP + pos] = (unsigned short)gid;
            }
}

__global__ __launch_bounds__(256) void gather(
    const float* __restrict__ params,
    const int* __restrict__ counts,
    const unsigned short* __restrict__ list,
    float2* __restrict__ out)
{
    const int tile = blockIdx.x;
    const int tz = tile / (TPD * TPD);
    const int rem = tile - tz * (TPD * TPD);
    const int ty = rem / TPD;
    const int tx = rem - ty * TPD;

    const int tid = threadIdx.x;
    const int lz = tid >> 6;            // wave id = z-slice
    const int ly = (tid >> 3) & 7;
    const int lx = tid & 7;
    const int iz0 = tz * TS + lz;       // voxel 0
    const int iz1 = iz0 + 4;            // voxel 1 (same y,x)
    const int iy = ty * TS + ly;
    const int ix = tx * TS + lx;
    const float fz0 = (float)iz0, fz1 = (float)iz1;
    const float fy = (float)iy, fx = (float)ix;

    __shared__ float4 sP[64][4];

    int cnt = counts[tile];
    if (cnt > CAP) cnt = CAP;
    const float4* p4 = reinterpret_cast<const float4*>(params);
    const unsigned short* tl = list + (size_t)tile * CAP;

    float a0r = 0.f, a0i = 0.f, a1r = 0.f, a1i = 0.f;

    for (int b0 = 0; b0 < cnt; b0 += 64) {
        const int nb = min(64, cnt - b0);
        __syncthreads();
        const int slot = tid >> 2;
        if (slot < nb) {
            const int gid = tl[b0 + slot];
            sP[slot][tid & 3] = p4[(size_t)gid * 4 + (tid & 3)];
        }
        __syncthreads();

        for (int g = 0; g < nb; ++g) {
            const float4 Pa = sP[g][0];
            const float4 Pb = sP[g][1];
            const float4 Pc = sP[g][2];
            const int loPack = __float_as_int(Pc.w);
            const int upPack = __float_as_int(sP[g][3].x);
            const int loy_ = (loPack >> 8) & 255, lox_ = (loPack >> 16) & 255;
            const int upy_ = upPack & 255,        upx_ = (upPack >> 8) & 255;
            if (iy < loy_ || iy > upy_ || ix < lox_ || ix > upx_) continue;
            const int loz_ = loPack & 255, upz_ = (loPack >> 24) & 255;

            const float dy = fy - Pb.w;
            const float dx = fx - Pc.x;
            // C = q11*dy^2 + q12*dy*dx + q22*dx^2 ; B = q01*dy + q02*dx
            const float Cc = fmaf(dy, fmaf(Pa.w, dy, Pb.x * dx), Pb.y * dx * dx);
            const float Bc = fmaf(Pa.y, dy, Pa.z * dx);

            if (iz0 >= loz_ && iz0 <= upz_) {
                const float dz = fz0 - Pb.z;
                const float t = fmaf(dz, fmaf(Pa.x, dz, Bc), Cc);
                if (t > -13.9f) {       // w < ~9e-7: numerically invisible
                    const float wgt = __expf(t);
                    a0r = fmaf(wgt, Pc.y, a0r);
                    a0i = fmaf(wgt, Pc.z, a0i);
                }
            }
            if (iz1 >= loz_ && iz1 <= upz_) {
                const float dz = fz1 - Pb.z;
                const float t = fmaf(dz, fmaf(Pa.x, dz, Bc), Cc);
                if (t > -13.9f) {
                    const float wgt = __expf(t);
                    a1r = fmaf(wgt, Pc.y, a1r);
                    a1i = fmaf(wgt, Pc.z, a1i);
                }
            }
        }
    }

    out[((size_t)iz0 * GH + iy) * GW + ix] = make_float2(a0r, a0i);
    out[((size_t)iz1 * GH + iy) * GW + ix] = make_float2(a1r, a1i);
}

extern "C" void kernel_launch(void* const* d_in, const int* in_sizes, int n_in,
                              void* d_out, int out_size, void* d_ws, size_t ws_size,
                              hipStream_t stream) {
    const float* centers    = (const float*)d_in[0];
    const float* log_scales = (const float*)d_in[1];
    const float* quats      = (const float*)d_in[2];
    const float* rho        = (const float*)d_in[3];

    // workspace carve-up: params (1.6 MB) | counts (32 KB) | list (6.1 MB)
    float* params = (float*)d_ws;
    int* counts = (int*)(params + (size_t)NPTS * PSTRIDE);
    unsigned short* list = (unsigned short*)(counts + NT);

    hipMemsetAsync(counts, 0, NT * sizeof(int), stream);
    prep_bin<<<(NPTS + 255) / 256, 256, 0, stream>>>(centers, log_scales, quats,
                                                     rho, params, counts, list);
    // gather writes every voxel exactly once -> no d_out memset needed
    gather<<<NT, 256, 0, stream>>>(params, counts, list, (float2*)d_out);
}

// Round 3
// 175.719 us; speedup vs baseline: 12.3586x; 1.5270x over previous
//
#include <hip/hip_runtime.h>

// GaussianMRIModel: splat 25000 anisotropic 3D Gaussians into 160^3 x 2 fp32.
// R2: gather restructured to z-column-per-thread with the exp recurrence
//   w(z+1) = w(z)*u(z), u(z+1) = u(z)*v,  v = exp(-p00) per-gaussian const
// -> 2 transcendentals per (gaussian,thread) instead of 1 per 2 voxels.
// log2(e) folded into coefficients so v_exp_f32 (exp2) is used directly.
// prep split: param kernel (no atomics) + parallel bin kernel (1 lane/tile).

namespace {
constexpr int GD = 160, GH = 160, GW = 160;
constexpr int NPTS = 25000;
constexpr int PATCH = 20;
constexpr int TS  = 8;               // tile edge
constexpr int TPD = GD / TS;         // 20
constexpr int NT  = TPD * TPD * TPD; // 8000 tiles
constexpr int CAP = 384;             // per-tile bucket capacity (mean ~110)
constexpr int PSTRIDE = 16;          // floats per gaussian struct
constexpr float L2E = 1.4426950408889634f;
}

// Param struct (16 floats, 4x float4), coefficients pre-scaled by log2(e)
// and -0.5 folded so gather computes t in exp2 space directly:
//  P0 = (q00, q01, q02, q11)   q00=-0.5*L2E*p00, q01=-L2E*p01, ...
//  P1 = (q12, q22, cvz, cvy)
//  P2 = (cvx, r0, r1, loPack)  loPack = loz|loy<<8|lox<<16|upz<<24
//  P3 = (upPack, v, 0, 0)      upPack = upy|upx<<8 ; v = 2^(2*q00) = e^-p00

__global__ void prep_params(const float* __restrict__ centers,
                            const float* __restrict__ log_scales,
                            const float* __restrict__ quats,
                            const float* __restrict__ rho,
                            float* __restrict__ params)
{
    const int gid = blockIdx.x * blockDim.x + threadIdx.x;
    if (gid >= NPTS) return;

    const float r0 = rho[gid * 2 + 0];
    const float r1 = rho[gid * 2 + 1];
    const float s0 = __expf(log_scales[gid * 3 + 0]);
    const float s1 = __expf(log_scales[gid * 3 + 1]);
    const float s2 = __expf(log_scales[gid * 3 + 2]);

    const float smax = fmaxf(s0, fmaxf(s1, s2));
    const float rad  = smax * 3.0f;          // RADIUS_FACTOR
    const float amp2 = r0 * r0 + r1 * r1;

    const float cvz = centers[gid * 3 + 0] * (float)(GD - 1);
    const float cvy = centers[gid * 3 + 1] * (float)(GH - 1);
    const float cvx = centers[gid * 3 + 2] * (float)(GW - 1);

    const int bz = (int)floorf(cvz - rad);
    const int by = (int)floorf(cvy - rad);
    const int bx = (int)floorf(cvx - rad);
    const int hz = (int)ceilf(cvz + rad);
    const int hy = (int)ceilf(cvy + rad);
    const int hx = (int)ceilf(cvx + rad);

    // reference mask: idx>=0 && idx<dim && idx<=hi, idx in [base, base+19]
    const int loz = max(bz, 0), upz = min(min(hz, GD - 1), bz + PATCH - 1);
    const int loy = max(by, 0), upy = min(min(hy, GH - 1), by + PATCH - 1);
    const int lox = max(bx, 0), upx = min(min(hx, GW - 1), bx + PATCH - 1);

    const bool valid = (amp2 >= 1e-12f) && (rad >= 1e-3f) &&
                       (upz >= loz) && (upy >= loy) && (upx >= lox);

    const float q0 = quats[gid * 4 + 0], q1 = quats[gid * 4 + 1];
    const float q2 = quats[gid * 4 + 2], q3 = quats[gid * 4 + 3];
    float qn = sqrtf(q0 * q0 + q1 * q1 + q2 * q2 + q3 * q3);
    qn = fmaxf(qn, 1e-6f);
    const float w = q0 / qn, x = q1 / qn, y = q2 / qn, z = q3 / qn;

    const float R00 = w * w + x * x - y * y - z * z;
    const float R01 = 2.f * (x * y - w * z);
    const float R02 = 2.f * (x * z + w * y);
    const float R10 = 2.f * (x * y + w * z);
    const float R11 = w * w - x * x + y * y - z * z;
    const float R12 = 2.f * (y * z - w * x);
    const float R20 = 2.f * (x * z - w * y);
    const float R21 = 2.f * (y * z + w * x);
    const float R22 = w * w - x * x - y * y + z * z;

    const float c0 = fmaxf(s0, 1e-4f); const float i0 = 1.f / (c0 * c0);
    const float c1 = fmaxf(s1, 1e-4f); const float i1 = 1.f / (c1 * c1);
    const float c2 = fmaxf(s2, 1e-4f); const float i2 = 1.f / (c2 * c2);

    const float p00 = R00 * R00 * i0 + R01 * R01 * i1 + R02 * R02 * i2;
    const float p01 = R00 * R10 * i0 + R01 * R11 * i1 + R02 * R12 * i2;
    const float p02 = R00 * R20 * i0 + R01 * R21 * i1 + R02 * R22 * i2;
    const float p11 = R10 * R10 * i0 + R11 * R11 * i1 + R12 * R12 * i2;
    const float p12 = R10 * R20 * i0 + R11 * R21 * i1 + R12 * R22 * i2;
    const float p22 = R20 * R20 * i0 + R21 * R21 * i1 + R22 * R22 * i2;

    const float q00s = -0.5f * L2E * p00;
    const float v    = __builtin_amdgcn_exp2f(2.f * q00s);  // per-step u ratio

    // invalid -> empty box (lo=255 > up=0): bin and gather both skip naturally
    const int zl = valid ? loz : 255, zu = valid ? upz : 0;
    const int yl = valid ? loy : 255, yu = valid ? upy : 0;
    const int xl = valid ? lox : 255, xu = valid ? upx : 0;
    const int loPack = zl | (yl << 8) | (xl << 16) | (zu << 24);
    const int upPack = yu | (xu << 8);

    float4* P = reinterpret_cast<float4*>(params + (size_t)gid * PSTRIDE);
    P[0] = make_float4(q00s, -L2E * p01, -L2E * p02, -0.5f * L2E * p11);
    P[1] = make_float4(-L2E * p12, -0.5f * L2E * p22, cvz, cvy);
    P[2] = make_float4(cvx, r0, r1, __int_as_float(loPack));
    P[3] = make_float4(__int_as_float(upPack), v, 0.f, 0.f);
}

// One lane per (gaussian, candidate tile): box spans <=4 tiles/dim -> 64 lanes.
__global__ __launch_bounds__(256) void bin(const float* __restrict__ params,
                                           int* __restrict__ counts,
                                           unsigned short* __restrict__ list)
{
    const int t = blockIdx.x * 256 + threadIdx.x;   // grid sized to NPTS*64
    const int gid  = t >> 6;
    const int lane = t & 63;
    const int lo = __float_as_int(params[(size_t)gid * PSTRIDE + 11]);
    const int up = __float_as_int(params[(size_t)gid * PSTRIDE + 12]);
    const int tz0 = (lo & 255) >> 3,         tz1 = ((lo >> 24) & 255) >> 3;
    const int ty0 = ((lo >> 8) & 255) >> 3,  ty1 = (up & 255) >> 3;
    const int tx0 = ((lo >> 16) & 255) >> 3, tx1 = ((up >> 8) & 255) >> 3;
    const int tz = tz0 + (lane >> 4);
    const int ty = ty0 + ((lane >> 2) & 3);
    const int tx = tx0 + (lane & 3);
    if (tz > tz1 || ty > ty1 || tx > tx1) return;
    const int tile = (tz * TPD + ty) * TPD + tx;
    const int pos = atomicAdd(&counts[tile], 1);
    if (pos < CAP) list[(size_t)tile * CAP + pos] = (unsigned short)gid;
}

__global__ __launch_bounds__(64) void gather(
    const float* __restrict__ params,
    const int* __restrict__ counts,
    const unsigned short* __restrict__ list,
    float2* __restrict__ out)
{
    const int tile = blockIdx.x;
    const int tz = tile / (TPD * TPD);
    const int rem = tile - tz * (TPD * TPD);
    const int ty = rem / TPD;
    const int tx = rem - ty * TPD;

    const int lane = threadIdx.x;
    const int ly = lane >> 3, lx = lane & 7;
    const int iy = ty * TS + ly;
    const int ix = tx * TS + lx;
    const int z0 = tz * TS;
    const float fy = (float)iy, fx = (float)ix, fz = (float)z0;

    __shared__ float4 sP[64][4];

    int cnt = counts[tile];
    if (cnt > CAP) cnt = CAP;
    const float4* p4 = reinterpret_cast<const float4*>(params);
    const unsigned short* tl = list + (size_t)tile * CAP;

    float ar[8], ai[8];
#pragma unroll
    for (int i = 0; i < 8; ++i) { ar[i] = 0.f; ai[i] = 0.f; }

    for (int b0 = 0; b0 < cnt; b0 += 64) {
        const int nb = min(64, cnt - b0);
        __syncthreads();
        if (lane < nb) {
            const int gid = tl[b0 + lane];
            const float4* src = p4 + (size_t)gid * 4;
            sP[lane][0] = src[0];
            sP[lane][1] = src[1];
            sP[lane][2] = src[2];
            sP[lane][3] = src[3];
        }
        __syncthreads();

        for (int g = 0; g < nb; ++g) {
            const float4 Pa = sP[g][0];
            const float4 Pb = sP[g][1];
            const float4 Pc = sP[g][2];
            const float4 Pd = sP[g][3];
            const int lo = __float_as_int(Pc.w);
            const int up = __float_as_int(Pd.x);
            const int loy_ = (lo >> 8) & 255, lox_ = (lo >> 16) & 255;
            const int upy_ = up & 255,        upx_ = (up >> 8) & 255;
            if (iy < loy_ || iy > upy_ || ix < lox_ || ix > upx_) continue;
            const int zl = (lo & 255) - z0;          // may be <0 or >7
            const int zu = ((lo >> 24) & 255) - z0;

            const float dy = fy - Pb.w;
            const float dx = fx - Pc.x;
            const float C = fmaf(dy, fmaf(Pa.w, dy, Pb.x * dx), Pb.y * dx * dx);
            const float B = fmaf(Pa.y, dy, Pa.z * dx);
            const float dz = fz - Pb.z;
            const float t0 = fmaf(dz, fmaf(Pa.x, dz, B), C);
            const float dt = fmaf(Pa.x, fmaf(2.f, dz, 1.f), B);
            float w = __builtin_amdgcn_exp2f(t0);    // weight at z0
            float u = __builtin_amdgcn_exp2f(dt);    // ratio w(z+1)/w(z) at z0
            const float v = Pd.y;                    // ratio u(z+1)/u(z)
            const float r0 = Pc.y, r1 = Pc.z;
#pragma unroll
            for (int i = 0; i < 8; ++i) {
                const float wm = (i >= zl && i <= zu) ? w : 0.f;
                ar[i] = fmaf(wm, r0, ar[i]);
                ai[i] = fmaf(wm, r1, ai[i]);
                w *= u;
                u *= v;
            }
        }
    }

#pragma unroll
    for (int i = 0; i < 8; ++i)
        out[((size_t)(z0 + i) * GH + iy) * GW + ix] = make_float2(ar[i], ai[i]);
}

extern "C" void kernel_launch(void* const* d_in, const int* in_sizes, int n_in,
                              void* d_out, int out_size, void* d_ws, size_t ws_size,
                              hipStream_t stream) {
    const float* centers    = (const float*)d_in[0];
    const float* log_scales = (const float*)d_in[1];
    const float* quats      = (const float*)d_in[2];
    const float* rho        = (const float*)d_in[3];

    // workspace: params (1.6 MB) | counts (32 KB) | list (6.1 MB)
    float* params = (float*)d_ws;
    int* counts = (int*)(params + (size_t)NPTS * PSTRIDE);
    unsigned short* list = (unsigned short*)(counts + NT);

    hipMemsetAsync(counts, 0, NT * sizeof(int), stream);
    prep_params<<<(NPTS + 255) / 256, 256, 0, stream>>>(centers, log_scales,
                                                        quats, rho, params);
    bin<<<(NPTS * 64) / 256, 256, 0, stream>>>(params, counts, list);
    // gather writes every voxel exactly once -> no d_out memset needed
    gather<<<NT, 64, 0, stream>>>(params, counts, list, (float2*)d_out);
}